// Round 17
// baseline (550.652 us; speedup 1.0000x reference)
//
#include <hip/hip_runtime.h>
#include <stdint.h>

#define BATCH 8
#define NPTS  16384
#define BN    (BATCH * NPTS)
#define CH    512                 // points per LDS chunk (2 x 16 KB buffers)
#define NCH   (NPTS / CH)         // 32
#define QPB   256                 // 4 waves x 64 queries (2 A-frags per wave)
#define MARGIN 1.0e-2f            // >> 2*delta(double-bf16-split approx error)

typedef float f32x16 __attribute__((ext_vector_type(16)));
typedef short s16x8  __attribute__((ext_vector_type(8)));

// RNE f32->bf16 bits and back; split2: v = a + b + eps, |eps| <= 2^-18 |v|
__device__ __forceinline__ uint16_t bfr(float x) {
    uint32_t u = __float_as_uint(x);
    return (uint16_t)((u + 0x7FFFu + ((u >> 16) & 1u)) >> 16);
}
__device__ __forceinline__ float bff(uint16_t s) {
    return __uint_as_float(((uint32_t)s) << 16);
}
__device__ __forceinline__ void split2(float v, uint16_t* a, uint16_t* b) {
    *a = bfr(v); *b = bfr(v - bff(*a));
}
__device__ __forceinline__ uint32_t pk2(uint16_t lo, uint16_t hi) {
    return (uint32_t)lo | ((uint32_t)hi << 16);
}

#define F16(M_) M_(0) M_(1) M_(2) M_(3) M_(4) M_(5) M_(6) M_(7) \
                M_(8) M_(9) M_(10) M_(11) M_(12) M_(13) M_(14) M_(15)

#define MIN3(a, b, c) fminf(fminf((a), (b)), (c))

// ---- enc: per point, 16 bf16 B-slots = [1,1,Ya,Yb, H0,M0,H0,M0 | H1,M1,H1,M1, H2,M2,H2,M2]
__global__ __launch_bounds__(256) void enc_kernel(
    const float* __restrict__ Y, uint4* __restrict__ enc)
{
#pragma clang fp contract(off)
    const int g = blockIdx.x * 256 + threadIdx.x;     // 0..BN-1
    const int b = g >> 14, p = g & (NPTS - 1);
    const float y0 = Y[(size_t)g * 3 + 0];
    const float y1 = Y[(size_t)g * 3 + 1];
    const float y2 = Y[(size_t)g * 3 + 2];
    const float ys = (y0 * y0 + y1 * y1) + y2 * y2;   // np order (approx side)
    uint16_t Ya, Yb; split2(ys, &Ya, &Yb);
    uint16_t H0, M0; split2(-2.0f * y0, &H0, &M0);
    uint16_t H1, M1; split2(-2.0f * y1, &H1, &M1);
    uint16_t H2, M2; split2(-2.0f * y2, &H2, &M2);
    const uint16_t ONE = 0x3F80;
    const int ch = p >> 9, pp = p & (CH - 1);
    const size_t base = (size_t)(b * NCH + ch) * (2 * CH) + pp;
    enc[base]      = make_uint4(pk2(ONE, ONE), pk2(Ya, Yb), pk2(H0, M0), pk2(H0, M0));
    enc[base + CH] = make_uint4(pk2(H1, M1), pk2(H1, M1), pk2(H2, M2), pk2(H2, M2));
}

// A-fragment for one query (row = its col slot), k-slots of group hi
__device__ __forceinline__ s16x8 make_afr(const float* __restrict__ xp, int hi) {
#pragma clang fp contract(off)
    const float x0 = xp[0], x1 = xp[1], x2 = xp[2];
    const float xs = (x0 * x0 + x1 * x1) + x2 * x2;
    uint16_t Xa, Xb; split2(xs, &Xa, &Xb);
    uint16_t h0, m0; split2(x0, &h0, &m0);
    uint16_t h1, m1; split2(x1, &h1, &m1);
    uint16_t h2, m2; split2(x2, &h2, &m2);
    const uint16_t ONE = 0x3F80;
    s16x8 a;
    if (hi == 0) {
        a[0]=(short)Xa; a[1]=(short)Xb; a[2]=(short)ONE; a[3]=(short)ONE;
        a[4]=(short)h0; a[5]=(short)h0; a[6]=(short)m0;  a[7]=(short)m0;
    } else {
        a[0]=(short)h1; a[1]=(short)h1; a[2]=(short)m1;  a[3]=(short)m1;
        a[4]=(short)h2; a[5]=(short)h2; a[6]=(short)m2;  a[7]=(short)m2;
    }
    return a;
}

#define DECODE_DBX() \
    int dir, batch, xblk; \
    { const int g = blockIdx.x; \
      if (ndir == 2) { const int s = 2 * (g & 7) + ((g >> 3) & 1); \
          dir = s >> 3; batch = s & 7; xblk = g >> 4; } \
      else { dir = dir0; batch = g & 7; xblk = g >> 3; } }

#define STAGE(c, buf) { \
        const uint4* src_ = ep + (size_t)(c) * (2 * CH); \
        _Pragma("unroll") \
        for (int i_ = 0; i_ < 4; ++i_) \
            __builtin_amdgcn_global_load_lds( \
                (const __attribute__((address_space(1))) void*)(src_ + i_ * 256 + tid), \
                (__attribute__((address_space(3))) void*)&lds[buf][i_ * 256 + tid], \
                16, 0, 0); \
    }

// ============ sweep 1: per-query approx min m' -> mprime ============
__global__ __launch_bounds__(256, 4) void nn_sweep1(
    const float* __restrict__ xyz1, const float* __restrict__ xyz2,
    const uint4* __restrict__ encA, const uint4* __restrict__ encB,
    float* __restrict__ mprime, int ndir, int dir0)
{
#pragma clang fp contract(off)
    __shared__ uint4 lds[2][2 * CH];                   // 2 x 16 KB

    const int tid = threadIdx.x;
    const int l   = tid & 63;
    const int wv  = tid >> 6;
    const int col = l & 31;
    const int hi  = l >> 5;
    DECODE_DBX()

    const float* Xp = dir ? xyz2 : xyz1;
    const uint4* ep = (dir ? encB : encA) + (size_t)batch * (NCH * 2 * CH);
    const int bofs  = batch * NPTS;
    const int qbase = xblk * QPB + wv * 64;

    const f32x16 zf = {0.f,0.f,0.f,0.f,0.f,0.f,0.f,0.f,
                       0.f,0.f,0.f,0.f,0.f,0.f,0.f,0.f};

    // row calibration only (probe1), packed 16 x 8 bits
    int rowpack[4] = {0, 0, 0, 0};
    {
        s16x8 pa = {0,0,0,0,0,0,0,0}, pb = {0,0,0,0,0,0,0,0};
        if (hi == 0) { pa[0] = (short)bfr((float)col); pb[0] = (short)0x3F80; }
        const f32x16 rowp = __builtin_amdgcn_mfma_f32_32x32x16_bf16(pa, pb, zf, 0, 0, 0);
#define PR(i) rowpack[(i) >> 2] |= ((int)rowp[i] & 0xFF) << (((i) & 3) * 8);
        F16(PR)
#undef PR
    }

    const s16x8 afr0 = make_afr(Xp + (size_t)(bofs + qbase + col) * 3, hi);
    const s16x8 afr1 = make_afr(Xp + (size_t)(bofs + qbase + 32 + col) * 3, hi);

    const int ldsb = hi * CH + col;

    f32x16 run0, run1;
#define RINIT(i) run0[i] = __builtin_inff(); run1[i] = __builtin_inff();
    F16(RINIT)
#undef RINIT
    STAGE(0, 0);
    __syncthreads();
    int cur = 0;
    for (int c = 0; c < NCH; ++c) {
        if (c + 1 < NCH) STAGE(c + 1, cur ^ 1);
#pragma unroll
        for (int tp = 0; tp < CH / 64; ++tp) {
            const s16x8 bfA = *(const s16x8*)&lds[cur][ldsb + (2 * tp) * 32];
            const s16x8 bfB = *(const s16x8*)&lds[cur][ldsb + (2 * tp + 1) * 32];
            {
                const f32x16 aA = __builtin_amdgcn_mfma_f32_32x32x16_bf16(afr0, bfA, zf, 0, 0, 0);
                const f32x16 aB = __builtin_amdgcn_mfma_f32_32x32x16_bf16(afr0, bfB, zf, 0, 0, 0);
#define RM0(i) run0[i] = MIN3(run0[i], aA[i], aB[i]);
                F16(RM0)
#undef RM0
            }
            {
                const f32x16 aA = __builtin_amdgcn_mfma_f32_32x32x16_bf16(afr1, bfA, zf, 0, 0, 0);
                const f32x16 aB = __builtin_amdgcn_mfma_f32_32x32x16_bf16(afr1, bfB, zf, 0, 0, 0);
#define RM1(i) run1[i] = MIN3(run1[i], aA[i], aB[i]);
                F16(RM1)
#undef RM1
            }
        }
        __syncthreads();
        cur ^= 1;
    }
#pragma unroll
    for (int mk = 1; mk <= 16; mk <<= 1) {
#define XMIN(i) run0[i] = fminf(run0[i], __shfl_xor(run0[i], mk, 64)); \
                run1[i] = fminf(run1[i], __shfl_xor(run1[i], mk, 64));
        F16(XMIN)
#undef XMIN
    }
    if (col == 0) {                       // 2 lanes/wave write their hi's rows
        float* mp = mprime + (size_t)dir * BN + bofs + qbase;
#define WR(i) { const int rl = (rowpack[(i) >> 2] >> (((i) & 3) * 8)) & 0xFF; \
                mp[rl] = run0[i]; mp[32 + rl] = run1[i]; }
        F16(WR)
#undef WR
    }
}

// ====== sweep 2: candidates (C = -(m'+MARGIN)) + exact argmin ======
__global__ __launch_bounds__(256, 4) void nn_sweep2(
    const float* __restrict__ xyz1, const float* __restrict__ xyz2,
    const uint4* __restrict__ encA, const uint4* __restrict__ encB,
    const float* __restrict__ mprime, float* __restrict__ out,
    int ndir, int dir0)
{
#pragma clang fp contract(off)
    __shared__ uint4 lds[2][2 * CH];                   // 2 x 16 KB
    __shared__ unsigned long long keys[QPB];           // 2 KB

    const int tid = threadIdx.x;
    const int l   = tid & 63;
    const int wv  = tid >> 6;
    const int col = l & 31;
    const int hi  = l >> 5;
    DECODE_DBX()

    const float* Xp = dir ? xyz2 : xyz1;
    const float* Yp = dir ? xyz1 : xyz2;
    const uint4* ep = (dir ? encB : encA) + (size_t)batch * (NCH * 2 * CH);
    const int bofs  = batch * NPTS;
    const int qbase = xblk * QPB + wv * 64;

    keys[tid] = ~0ull;

    const f32x16 zf = {0.f,0.f,0.f,0.f,0.f,0.f,0.f,0.f,
                       0.f,0.f,0.f,0.f,0.f,0.f,0.f,0.f};

    // full (row,col) calibration packed to 8 ints
    int rcpack[8];
    {
        s16x8 pa = {0,0,0,0,0,0,0,0}, pb = {0,0,0,0,0,0,0,0};
        if (hi == 0) { pa[0] = (short)bfr((float)col); pb[0] = (short)0x3F80; }
        const f32x16 rowp = __builtin_amdgcn_mfma_f32_32x32x16_bf16(pa, pb, zf, 0, 0, 0);
        s16x8 pc = {0,0,0,0,0,0,0,0}, pd = {0,0,0,0,0,0,0,0};
        if (hi == 0) { pc[0] = (short)0x3F80; pd[0] = (short)bfr((float)col); }
        const f32x16 colp = __builtin_amdgcn_mfma_f32_32x32x16_bf16(pc, pd, zf, 0, 0, 0);
#define PACKRC(r) { const int e_ = ((int)rowp[r]) | (((int)colp[r]) << 8); \
                    if (((r) & 1) == 0) rcpack[(r) >> 1] = e_; \
                    else                rcpack[(r) >> 1] |= e_ << 16; }
        F16(PACKRC)
#undef PACKRC
    }

    const s16x8 afr0 = make_afr(Xp + (size_t)(bofs + qbase + col) * 3, hi);
    const s16x8 afr1 = make_afr(Xp + (size_t)(bofs + qbase + 32 + col) * 3, hi);

    // per-slot thresholds from sweep1's m'
    f32x16 cneg0, cneg1;
    {
        const float* mp = mprime + (size_t)dir * BN + bofs + qbase;
#define LDC(i) { const int e_ = (rcpack[(i) >> 1] >> (((i) & 1) * 16)) & 0xFFFF; \
                 const int rl = e_ & 0xFF; \
                 cneg0[i] = -(mp[rl] + MARGIN); cneg1[i] = -(mp[32 + rl] + MARGIN); }
        F16(LDC)
#undef LDC
    }

    const int ldsb = hi * CH + col;

#define HITR(accv, jb, foff, r) if ((accv)[r] <= 0.0f) { \
        const int w_  = rcpack[(r) >> 1]; \
        const int e_  = (w_ >> (((r) & 1) * 16)) & 0xFFFF; \
        const int rl  = e_ & 0xFF; \
        const int jc  = (jb) + (e_ >> 8); \
        const float* xq = Xp + (size_t)(bofs + qbase + (foff) + rl) * 3; \
        const float qx0 = xq[0], qx1 = xq[1], qx2 = xq[2]; \
        const float qxs = (qx0 * qx0 + qx1 * qx1) + qx2 * qx2; \
        const float* yq = Yp + (size_t)(bofs + jc) * 3; \
        const float py0 = yq[0], py1 = yq[1], py2 = yq[2]; \
        const float pys = (py0 * py0 + py1 * py1) + py2 * py2; \
        const float dd = (qxs - 2.0f * ((qx0 * py0 + qx1 * py1) + qx2 * py2)) + pys; \
        uint32_t kb = __float_as_uint(dd); \
        kb = (kb & 0x80000000u) ? ~kb : (kb | 0x80000000u); \
        atomicMin(&keys[wv * 64 + (foff) + rl], \
                  ((unsigned long long)kb << 32) | (uint32_t)jc); }
#define F16_HIT(accv, jb, foff) \
        HITR(accv, jb, foff, 0) HITR(accv, jb, foff, 1) HITR(accv, jb, foff, 2) HITR(accv, jb, foff, 3) \
        HITR(accv, jb, foff, 4) HITR(accv, jb, foff, 5) HITR(accv, jb, foff, 6) HITR(accv, jb, foff, 7) \
        HITR(accv, jb, foff, 8) HITR(accv, jb, foff, 9) HITR(accv, jb, foff, 10) HITR(accv, jb, foff, 11) \
        HITR(accv, jb, foff, 12) HITR(accv, jb, foff, 13) HITR(accv, jb, foff, 14) HITR(accv, jb, foff, 15)
#define HIT16(accv, jb, foff) { \
        const float u0 = MIN3((accv)[0],  (accv)[1],  (accv)[2]); \
        const float u1 = MIN3((accv)[3],  (accv)[4],  (accv)[5]); \
        const float u2 = MIN3((accv)[6],  (accv)[7],  (accv)[8]); \
        const float u3 = MIN3((accv)[9],  (accv)[10], (accv)[11]); \
        const float u4 = MIN3((accv)[12], (accv)[13], (accv)[14]); \
        const float v0 = MIN3(u0, u1, (accv)[15]); \
        const float v1 = MIN3(u2, u3, u4); \
        if (fminf(v0, v1) <= 0.0f) { F16_HIT(accv, jb, foff) } }

    STAGE(0, 0);
    __syncthreads();
    int cur = 0;
    for (int c = 0; c < NCH; ++c) {
        if (c + 1 < NCH) STAGE(c + 1, cur ^ 1);
#pragma unroll
        for (int tp = 0; tp < CH / 64; ++tp) {
            const s16x8 bfA = *(const s16x8*)&lds[cur][ldsb + (2 * tp) * 32];
            const s16x8 bfB = *(const s16x8*)&lds[cur][ldsb + (2 * tp + 1) * 32];
            const int jbA = c * CH + (2 * tp) * 32;
            {
                const f32x16 aA = __builtin_amdgcn_mfma_f32_32x32x16_bf16(afr0, bfA, cneg0, 0, 0, 0);
                const f32x16 aB = __builtin_amdgcn_mfma_f32_32x32x16_bf16(afr0, bfB, cneg0, 0, 0, 0);
                HIT16(aA, jbA, 0)
                HIT16(aB, jbA + 32, 0)
            }
            {
                const f32x16 aA = __builtin_amdgcn_mfma_f32_32x32x16_bf16(afr1, bfA, cneg1, 0, 0, 0);
                const f32x16 aB = __builtin_amdgcn_mfma_f32_32x32x16_bf16(afr1, bfB, cneg1, 0, 0, 0);
                HIT16(aA, jbA, 32)
                HIT16(aB, jbA + 32, 32)
            }
        }
        __syncthreads();
        cur ^= 1;
    }
#undef HIT16
#undef F16_HIT
#undef HITR

    __syncthreads();
    {
        const unsigned long long m = keys[tid];
        const uint32_t k32 = (uint32_t)(m >> 32);
        const uint32_t db  = (k32 & 0x80000000u) ? (k32 ^ 0x80000000u) : ~k32;
        const size_t gq = (size_t)bofs + (size_t)xblk * QPB + tid;
        float* distp = out + (size_t)dir * BN;
        float* idxp  = out + (size_t)(2 + dir) * BN;
        distp[gq] = __uint_as_float(db);
        idxp[gq]  = (float)(uint32_t)(m & 0xFFFFFFFFu);
    }
}

extern "C" void kernel_launch(void* const* d_in, const int* in_sizes, int n_in,
                              void* d_out, int out_size, void* d_ws, size_t ws_size,
                              hipStream_t stream) {
    const float* xyz1 = (const float*)d_in[0];
    const float* xyz2 = (const float*)d_in[1];
    float* out = (float*)d_out;

    uint4* encA   = (uint4*)d_ws;                       // 4 MiB
    uint4* encB   = encA + (size_t)BN * 2;              // 4 MiB
    float* mpri   = (float*)(encB + (size_t)BN * 2);    // 1 MiB (2 x BN f32)

    if (ws_size >= (size_t)10 * 1024 * 1024) {
        enc_kernel<<<BN / 256, 256, 0, stream>>>(xyz2, encA);
        enc_kernel<<<BN / 256, 256, 0, stream>>>(xyz1, encB);
        nn_sweep1<<<1024, 256, 0, stream>>>(xyz1, xyz2, encA, encB, mpri, 2, 0);
        nn_sweep2<<<1024, 256, 0, stream>>>(xyz1, xyz2, encA, encB, mpri, out, 2, 0);
    } else {                                  // sequential, reuse encA
        float* mp2 = (float*)(encA + (size_t)BN * 2);
        enc_kernel<<<BN / 256, 256, 0, stream>>>(xyz2, encA);
        nn_sweep1<<<512, 256, 0, stream>>>(xyz1, xyz2, encA, encA, mp2, 1, 0);
        nn_sweep2<<<512, 256, 0, stream>>>(xyz1, xyz2, encA, encA, mp2, out, 1, 0);
        enc_kernel<<<BN / 256, 256, 0, stream>>>(xyz1, encA);
        nn_sweep1<<<512, 256, 0, stream>>>(xyz1, xyz2, encA, encA, mp2, 1, 1);
        nn_sweep2<<<512, 256, 0, stream>>>(xyz1, xyz2, encA, encA, mp2, out, 1, 1);
    }
}

// Round 18
// 408.211 us; speedup vs baseline: 1.3489x; 1.3489x over previous
//
#include <hip/hip_runtime.h>
#include <stdint.h>

#define BATCH 8
#define NPTS  16384
#define BN    (BATCH * NPTS)
#define CH    512                 // points per LDS chunk (2 x 16 KB buffers)
#define NCH   (NPTS / CH)         // 32
#define QPB   256                 // 4 waves x 64 queries (2 query B-frags/wave)
#define MARGIN 1.0e-2f            // >> 2*delta(double-bf16-split approx error)

typedef float f32x16 __attribute__((ext_vector_type(16)));
typedef short s16x8  __attribute__((ext_vector_type(8)));

// RNE f32->bf16 bits and back; split2: v = a + b + eps, |eps| <= 2^-18 |v|
__device__ __forceinline__ uint16_t bfr(float x) {
    uint32_t u = __float_as_uint(x);
    return (uint16_t)((u + 0x7FFFu + ((u >> 16) & 1u)) >> 16);
}
__device__ __forceinline__ float bff(uint16_t s) {
    return __uint_as_float(((uint32_t)s) << 16);
}
__device__ __forceinline__ void split2(float v, uint16_t* a, uint16_t* b) {
    *a = bfr(v); *b = bfr(v - bff(*a));
}
__device__ __forceinline__ uint32_t pk2(uint16_t lo, uint16_t hi) {
    return (uint32_t)lo | ((uint32_t)hi << 16);
}

#define F16(M_) M_(0) M_(1) M_(2) M_(3) M_(4) M_(5) M_(6) M_(7) \
                M_(8) M_(9) M_(10) M_(11) M_(12) M_(13) M_(14) M_(15)

#define MIN3(a, b, c) fminf(fminf((a), (b)), (c))

__device__ __forceinline__ float fold16(const f32x16 a) {
    const float u0 = MIN3(a[0],  a[1],  a[2]);
    const float u1 = MIN3(a[3],  a[4],  a[5]);
    const float u2 = MIN3(a[6],  a[7],  a[8]);
    const float u3 = MIN3(a[9],  a[10], a[11]);
    const float u4 = MIN3(a[12], a[13], a[14]);
    const float v0 = MIN3(u0, u1, a[15]);
    const float v1 = MIN3(u2, u3, u4);
    return fminf(v0, v1);
}

// ---- enc: per point, 16 bf16 slots = [1,1,Ya,Yb, H0,M0,H0,M0 | H1,M1,H1,M1, H2,M2,H2,M2]
// (Ya,Yb)=split2(ys), (Hd,Md)=split2(-2*yd). Layout [b][chunk][half][p] of uint4.
__global__ __launch_bounds__(256) void enc_kernel(
    const float* __restrict__ Y, uint4* __restrict__ enc)
{
#pragma clang fp contract(off)
    const int g = blockIdx.x * 256 + threadIdx.x;     // 0..BN-1
    const int b = g >> 14, p = g & (NPTS - 1);
    const float y0 = Y[(size_t)g * 3 + 0];
    const float y1 = Y[(size_t)g * 3 + 1];
    const float y2 = Y[(size_t)g * 3 + 2];
    const float ys = (y0 * y0 + y1 * y1) + y2 * y2;   // np order (approx side)
    uint16_t Ya, Yb; split2(ys, &Ya, &Yb);
    uint16_t H0, M0; split2(-2.0f * y0, &H0, &M0);
    uint16_t H1, M1; split2(-2.0f * y1, &H1, &M1);
    uint16_t H2, M2; split2(-2.0f * y2, &H2, &M2);
    const uint16_t ONE = 0x3F80;
    const int ch = p >> 9, pp = p & (CH - 1);
    const size_t base = (size_t)(b * NCH + ch) * (2 * CH) + pp;
    enc[base]      = make_uint4(pk2(ONE, ONE), pk2(Ya, Yb), pk2(H0, M0), pk2(H0, M0));
    enc[base + CH] = make_uint4(pk2(H1, M1), pk2(H1, M1), pk2(H2, M2), pk2(H2, M2));
}

#define DECODE_DBX() \
    int dir, batch, xblk; \
    { const int g = blockIdx.x; \
      if (ndir == 2) { const int s = 2 * (g & 7) + ((g >> 3) & 1); \
          dir = s >> 3; batch = s & 7; xblk = g >> 4; } \
      else { dir = dir0; batch = g & 7; xblk = g >> 3; } }

#define STAGE(c, buf) { \
        const uint4* src_ = ep + (size_t)(c) * (2 * CH); \
        _Pragma("unroll") \
        for (int i_ = 0; i_ < 4; ++i_) \
            __builtin_amdgcn_global_load_lds( \
                (const __attribute__((address_space(1))) void*)(src_ + i_ * 256 + tid), \
                (__attribute__((address_space(3))) void*)&lds[buf][i_ * 256 + tid], \
                16, 0, 0); \
    }

// query B-fragment (col = lane's col slot), k-slots of group hi; also returns
// the raw query coords for the exact-eval path
#define MKQFR(dst, qq, qx0v, qx1v, qx2v, qxsv) { \
        const float* xp = Xp + (size_t)(bofs + (qq)) * 3; \
        qx0v = xp[0]; qx1v = xp[1]; qx2v = xp[2]; \
        qxsv = (qx0v * qx0v + qx1v * qx1v) + qx2v * qx2v; \
        uint16_t Xa, Xb; split2(qxsv, &Xa, &Xb); \
        uint16_t h0, m0; split2(qx0v, &h0, &m0); \
        uint16_t h1, m1; split2(qx1v, &h1, &m1); \
        uint16_t h2, m2; split2(qx2v, &h2, &m2); \
        const uint16_t ONE = 0x3F80; \
        if (hi == 0) { \
            dst[0]=(short)Xa; dst[1]=(short)Xb; dst[2]=(short)ONE; dst[3]=(short)ONE; \
            dst[4]=(short)h0; dst[5]=(short)h0; dst[6]=(short)m0;  dst[7]=(short)m0; \
        } else { \
            dst[0]=(short)h1; dst[1]=(short)h1; dst[2]=(short)m1;  dst[3]=(short)m1; \
            dst[4]=(short)h2; dst[5]=(short)h2; dst[6]=(short)m2;  dst[7]=(short)m2; \
        } }

// ============ sweep 1: per-query approx min m' -> mprime ============
// Operand-swapped MFMA: A = point tile (LDS), B = query frag. Each lane's 16
// acc regs all belong to ITS query col -> running min is ONE scalar.
__global__ __launch_bounds__(256, 4) void nn_sweep1(
    const float* __restrict__ xyz1, const float* __restrict__ xyz2,
    const uint4* __restrict__ encA, const uint4* __restrict__ encB,
    float* __restrict__ mprime, int ndir, int dir0)
{
#pragma clang fp contract(off)
    __shared__ uint4 lds[2][2 * CH];                   // 2 x 16 KB

    const int tid = threadIdx.x;
    const int l   = tid & 63;
    const int wv  = tid >> 6;
    const int col = l & 31;
    const int hi  = l >> 5;
    DECODE_DBX()

    const float* Xp = dir ? xyz2 : xyz1;
    const uint4* ep = (dir ? encB : encA) + (size_t)batch * (NCH * 2 * CH);
    const int bofs  = batch * NPTS;
    const int qbase = xblk * QPB + wv * 64;

    const f32x16 zf = {0.f,0.f,0.f,0.f,0.f,0.f,0.f,0.f,
                       0.f,0.f,0.f,0.f,0.f,0.f,0.f,0.f};

    s16x8 qfr0, qfr1;
    float qa0, qa1, qa2, qas, qb0, qb1, qb2, qbs;
    MKQFR(qfr0, qbase + col,      qa0, qa1, qa2, qas)
    MKQFR(qfr1, qbase + 32 + col, qb0, qb1, qb2, qbs)
    (void)qa0; (void)qb0;  // coords unused in sweep1

    const int ldsb = hi * CH + col;

    float run0 = __builtin_inff(), run1 = __builtin_inff();
    STAGE(0, 0);
    __syncthreads();
    int cur = 0;
    for (int c = 0; c < NCH; ++c) {
        if (c + 1 < NCH) STAGE(c + 1, cur ^ 1);
#pragma unroll
        for (int tp = 0; tp < CH / 64; ++tp) {
            const s16x8 pA = *(const s16x8*)&lds[cur][ldsb + (2 * tp) * 32];
            const s16x8 pB = *(const s16x8*)&lds[cur][ldsb + (2 * tp + 1) * 32];
            const f32x16 a0 = __builtin_amdgcn_mfma_f32_32x32x16_bf16(pA, qfr0, zf, 0, 0, 0);
            const f32x16 a1 = __builtin_amdgcn_mfma_f32_32x32x16_bf16(pA, qfr1, zf, 0, 0, 0);
            const f32x16 a2 = __builtin_amdgcn_mfma_f32_32x32x16_bf16(pB, qfr0, zf, 0, 0, 0);
            const f32x16 a3 = __builtin_amdgcn_mfma_f32_32x32x16_bf16(pB, qfr1, zf, 0, 0, 0);
            run0 = MIN3(run0, fold16(a0), fold16(a2));
            run1 = MIN3(run1, fold16(a1), fold16(a3));
        }
        __syncthreads();
        cur ^= 1;
    }
    // combine the two hi-halves (complementary point rows, same query col)
    run0 = fminf(run0, __shfl_xor(run0, 32, 64));
    run1 = fminf(run1, __shfl_xor(run1, 32, 64));
    if (l < 32) {
        float* mp = mprime + (size_t)dir * BN + bofs + qbase;
        mp[col]      = run0;
        mp[32 + col] = run1;
    }
}

// ====== sweep 2: candidates (d <= m'+MARGIN) + exact argmin ======
__global__ __launch_bounds__(256, 4) void nn_sweep2(
    const float* __restrict__ xyz1, const float* __restrict__ xyz2,
    const uint4* __restrict__ encA, const uint4* __restrict__ encB,
    const float* __restrict__ mprime, float* __restrict__ out,
    int ndir, int dir0)
{
#pragma clang fp contract(off)
    __shared__ uint4 lds[2][2 * CH];                   // 2 x 16 KB
    __shared__ unsigned long long keys[QPB];           // 2 KB

    const int tid = threadIdx.x;
    const int l   = tid & 63;
    const int wv  = tid >> 6;
    const int col = l & 31;
    const int hi  = l >> 5;
    DECODE_DBX()

    const float* Xp = dir ? xyz2 : xyz1;
    const float* Yp = dir ? xyz1 : xyz2;
    const uint4* ep = (dir ? encB : encA) + (size_t)batch * (NCH * 2 * CH);
    const int bofs  = batch * NPTS;
    const int qbase = xblk * QPB + wv * 64;

    keys[tid] = ~0ull;

    const f32x16 zf = {0.f,0.f,0.f,0.f,0.f,0.f,0.f,0.f,
                       0.f,0.f,0.f,0.f,0.f,0.f,0.f,0.f};

    // A-side row calibration (point rows), packed 16 x 8 bits
    int rowpack[4] = {0, 0, 0, 0};
    {
        s16x8 pa = {0,0,0,0,0,0,0,0}, pb = {0,0,0,0,0,0,0,0};
        if (hi == 0) { pa[0] = (short)bfr((float)col); pb[0] = (short)0x3F80; }
        const f32x16 rowp = __builtin_amdgcn_mfma_f32_32x32x16_bf16(pa, pb, zf, 0, 0, 0);
#define PR(i) rowpack[(i) >> 2] |= ((int)rowp[i] & 0xFF) << (((i) & 3) * 8);
        F16(PR)
#undef PR
    }

    s16x8 qfr0, qfr1;
    float qa0, qa1, qa2, qas, qb0, qb1, qb2, qbs;
    MKQFR(qfr0, qbase + col,      qa0, qa1, qa2, qas)
    MKQFR(qfr1, qbase + 32 + col, qb0, qb1, qb2, qbs)

    // per-lane scalar thresholds from sweep1
    float thr0, thr1;
    {
        const float* mp = mprime + (size_t)dir * BN + bofs + qbase;
        thr0 = mp[col] + MARGIN;
        thr1 = mp[32 + col] + MARGIN;
    }

    const int ldsb = hi * CH + col;

    // HIT: per-acc candidate scan. Query coords are hoisted lane constants.
#define HITR(accv, jb, foff, thr, qx0, qx1, qx2, qxs, r) \
        if ((accv)[r] <= (thr)) { \
            const int jc = (jb) + ((rowpack[(r) >> 2] >> (((r) & 3) * 8)) & 0xFF); \
            const float* yq = Yp + (size_t)(bofs + jc) * 3; \
            const float py0 = yq[0], py1 = yq[1], py2 = yq[2]; \
            const float pys = (py0 * py0 + py1 * py1) + py2 * py2; \
            const float dd = ((qxs) - 2.0f * (((qx0) * py0 + (qx1) * py1) + (qx2) * py2)) + pys; \
            uint32_t kb = __float_as_uint(dd); \
            kb = (kb & 0x80000000u) ? ~kb : (kb | 0x80000000u); \
            atomicMin(&keys[wv * 64 + (foff) + col], \
                      ((unsigned long long)kb << 32) | (uint32_t)jc); }
#define HIT(accv, jb, foff, thr, qx0, qx1, qx2, qxs) \
        if (fold16(accv) <= (thr)) { \
            HITR(accv, jb, foff, thr, qx0, qx1, qx2, qxs, 0) \
            HITR(accv, jb, foff, thr, qx0, qx1, qx2, qxs, 1) \
            HITR(accv, jb, foff, thr, qx0, qx1, qx2, qxs, 2) \
            HITR(accv, jb, foff, thr, qx0, qx1, qx2, qxs, 3) \
            HITR(accv, jb, foff, thr, qx0, qx1, qx2, qxs, 4) \
            HITR(accv, jb, foff, thr, qx0, qx1, qx2, qxs, 5) \
            HITR(accv, jb, foff, thr, qx0, qx1, qx2, qxs, 6) \
            HITR(accv, jb, foff, thr, qx0, qx1, qx2, qxs, 7) \
            HITR(accv, jb, foff, thr, qx0, qx1, qx2, qxs, 8) \
            HITR(accv, jb, foff, thr, qx0, qx1, qx2, qxs, 9) \
            HITR(accv, jb, foff, thr, qx0, qx1, qx2, qxs, 10) \
            HITR(accv, jb, foff, thr, qx0, qx1, qx2, qxs, 11) \
            HITR(accv, jb, foff, thr, qx0, qx1, qx2, qxs, 12) \
            HITR(accv, jb, foff, thr, qx0, qx1, qx2, qxs, 13) \
            HITR(accv, jb, foff, thr, qx0, qx1, qx2, qxs, 14) \
            HITR(accv, jb, foff, thr, qx0, qx1, qx2, qxs, 15) \
        }

    STAGE(0, 0);
    __syncthreads();
    int cur = 0;
    for (int c = 0; c < NCH; ++c) {
        if (c + 1 < NCH) STAGE(c + 1, cur ^ 1);
#pragma unroll
        for (int tp = 0; tp < CH / 64; ++tp) {
            const s16x8 pA = *(const s16x8*)&lds[cur][ldsb + (2 * tp) * 32];
            const s16x8 pB = *(const s16x8*)&lds[cur][ldsb + (2 * tp + 1) * 32];
            const int jbA = c * CH + (2 * tp) * 32;
            {
                const f32x16 a0 = __builtin_amdgcn_mfma_f32_32x32x16_bf16(pA, qfr0, zf, 0, 0, 0);
                const f32x16 a2 = __builtin_amdgcn_mfma_f32_32x32x16_bf16(pB, qfr0, zf, 0, 0, 0);
                HIT(a0, jbA,      0, thr0, qa0, qa1, qa2, qas)
                HIT(a2, jbA + 32, 0, thr0, qa0, qa1, qa2, qas)
            }
            {
                const f32x16 a1 = __builtin_amdgcn_mfma_f32_32x32x16_bf16(pA, qfr1, zf, 0, 0, 0);
                const f32x16 a3 = __builtin_amdgcn_mfma_f32_32x32x16_bf16(pB, qfr1, zf, 0, 0, 0);
                HIT(a1, jbA,      32, thr1, qb0, qb1, qb2, qbs)
                HIT(a3, jbA + 32, 32, thr1, qb0, qb1, qb2, qbs)
            }
        }
        __syncthreads();
        cur ^= 1;
    }
#undef HIT
#undef HITR

    __syncthreads();
    {
        const unsigned long long m = keys[tid];
        const uint32_t k32 = (uint32_t)(m >> 32);
        const uint32_t db  = (k32 & 0x80000000u) ? (k32 ^ 0x80000000u) : ~k32;
        const size_t gq = (size_t)bofs + (size_t)xblk * QPB + tid;
        float* distp = out + (size_t)dir * BN;
        float* idxp  = out + (size_t)(2 + dir) * BN;
        distp[gq] = __uint_as_float(db);
        idxp[gq]  = (float)(uint32_t)(m & 0xFFFFFFFFu);
    }
}

extern "C" void kernel_launch(void* const* d_in, const int* in_sizes, int n_in,
                              void* d_out, int out_size, void* d_ws, size_t ws_size,
                              hipStream_t stream) {
    const float* xyz1 = (const float*)d_in[0];
    const float* xyz2 = (const float*)d_in[1];
    float* out = (float*)d_out;

    uint4* encA   = (uint4*)d_ws;                       // 4 MiB
    uint4* encB   = encA + (size_t)BN * 2;              // 4 MiB
    float* mpri   = (float*)(encB + (size_t)BN * 2);    // 1 MiB (2 x BN f32)

    if (ws_size >= (size_t)10 * 1024 * 1024) {
        enc_kernel<<<BN / 256, 256, 0, stream>>>(xyz2, encA);
        enc_kernel<<<BN / 256, 256, 0, stream>>>(xyz1, encB);
        nn_sweep1<<<1024, 256, 0, stream>>>(xyz1, xyz2, encA, encB, mpri, 2, 0);
        nn_sweep2<<<1024, 256, 0, stream>>>(xyz1, xyz2, encA, encB, mpri, out, 2, 0);
    } else {                                  // sequential, reuse encA
        float* mp2 = (float*)(encA + (size_t)BN * 2);
        enc_kernel<<<BN / 256, 256, 0, stream>>>(xyz2, encA);
        nn_sweep1<<<512, 256, 0, stream>>>(xyz1, xyz2, encA, encA, mp2, 1, 0);
        nn_sweep2<<<512, 256, 0, stream>>>(xyz1, xyz2, encA, encA, mp2, out, 1, 0);
        enc_kernel<<<BN / 256, 256, 0, stream>>>(xyz1, encA);
        nn_sweep1<<<512, 256, 0, stream>>>(xyz1, xyz2, encA, encA, mp2, 1, 1);
        nn_sweep2<<<512, 256, 0, stream>>>(xyz1, xyz2, encA, encA, mp2, out, 1, 1);
    }
}

// Round 19
// 372.196 us; speedup vs baseline: 1.4795x; 1.0968x over previous
//
#include <hip/hip_runtime.h>
#include <stdint.h>

#define BATCH 8
#define NPTS  16384
#define BN    (BATCH * NPTS)
#define CH    256                 // points per LDS chunk (2 x 8 KB buffers)
#define NCH   (NPTS / CH)         // 64
#define QPB   256                 // 4 waves x 64 queries (2 query B-frags/wave)
#define MARGIN 4.0e-3f            // >= 2.6x worst-stack approx error (~1.5e-3)

typedef float f32x16 __attribute__((ext_vector_type(16)));
typedef short s16x8  __attribute__((ext_vector_type(8)));

__device__ __forceinline__ uint16_t bfr(float x) {
    uint32_t u = __float_as_uint(x);
    return (uint16_t)((u + 0x7FFFu + ((u >> 16) & 1u)) >> 16);
}
__device__ __forceinline__ float bff(uint16_t s) {
    return __uint_as_float(((uint32_t)s) << 16);
}
__device__ __forceinline__ void split2(float v, uint16_t* a, uint16_t* b) {
    *a = bfr(v); *b = bfr(v - bff(*a));
}
__device__ __forceinline__ uint32_t pk2(uint16_t lo, uint16_t hi) {
    return (uint32_t)lo | ((uint32_t)hi << 16);
}
// monotone f32 <-> u32 order map (handles negatives from cancellation)
__device__ __forceinline__ uint32_t key32(float d) {
    uint32_t b = __float_as_uint(d);
    return (b & 0x80000000u) ? ~b : (b | 0x80000000u);
}
__device__ __forceinline__ float dec32(uint32_t k) {
    return __uint_as_float((k & 0x80000000u) ? (k ^ 0x80000000u) : ~k);
}

#define F16(M_) M_(0) M_(1) M_(2) M_(3) M_(4) M_(5) M_(6) M_(7) \
                M_(8) M_(9) M_(10) M_(11) M_(12) M_(13) M_(14) M_(15)

#define MIN3(a, b, c) fminf(fminf((a), (b)), (c))

__device__ __forceinline__ float fold16(const f32x16 a) {
    const float u0 = MIN3(a[0],  a[1],  a[2]);
    const float u1 = MIN3(a[3],  a[4],  a[5]);
    const float u2 = MIN3(a[6],  a[7],  a[8]);
    const float u3 = MIN3(a[9],  a[10], a[11]);
    const float u4 = MIN3(a[12], a[13], a[14]);
    const float v0 = MIN3(u0, u1, a[15]);
    const float v1 = MIN3(u2, u3, u4);
    return fminf(v0, v1);
}

// ---- enc: per point, 16 bf16 slots = [1,1,Ya,Yb, H0,M0,H0,M0 | H1,M1,H1,M1, H2,M2,H2,M2]
__global__ __launch_bounds__(256) void enc_kernel(
    const float* __restrict__ Y, uint4* __restrict__ enc)
{
#pragma clang fp contract(off)
    const int g = blockIdx.x * 256 + threadIdx.x;     // 0..BN-1
    const int b = g >> 14, p = g & (NPTS - 1);
    const float y0 = Y[(size_t)g * 3 + 0];
    const float y1 = Y[(size_t)g * 3 + 1];
    const float y2 = Y[(size_t)g * 3 + 2];
    const float ys = (y0 * y0 + y1 * y1) + y2 * y2;   // np order (approx side)
    uint16_t Ya, Yb; split2(ys, &Ya, &Yb);
    uint16_t H0, M0; split2(-2.0f * y0, &H0, &M0);
    uint16_t H1, M1; split2(-2.0f * y1, &H1, &M1);
    uint16_t H2, M2; split2(-2.0f * y2, &H2, &M2);
    const uint16_t ONE = 0x3F80;
    const int ch = p >> 8, pp = p & (CH - 1);
    const size_t base = (size_t)(b * NCH + ch) * (2 * CH) + pp;
    enc[base]      = make_uint4(pk2(ONE, ONE), pk2(Ya, Yb), pk2(H0, M0), pk2(H0, M0));
    enc[base + CH] = make_uint4(pk2(H1, M1), pk2(H1, M1), pk2(H2, M2), pk2(H2, M2));
}

// decode (dir,batch,kh,xblk); ksplit=2: grid 2048, each block half the points
#define DECODE_DBX() \
    int dir, batch, kh, xblk; \
    { const int g = blockIdx.x; \
      const int s = 2 * (g & 7) + ((g >> 3) & 1); \
      dir = s >> 3; batch = s & 7; \
      if (ksplit == 2) { kh = (g >> 4) & 1; xblk = g >> 5; } \
      else             { kh = 0;            xblk = g >> 4; } }

#define STAGE(c, buf) { \
        const uint4* src_ = ep + (size_t)(c) * (2 * CH); \
        _Pragma("unroll") \
        for (int i_ = 0; i_ < 2; ++i_) \
            __builtin_amdgcn_global_load_lds( \
                (const __attribute__((address_space(1))) void*)(src_ + i_ * 256 + tid), \
                (__attribute__((address_space(3))) void*)&lds[buf][i_ * 256 + tid], \
                16, 0, 0); \
    }

#define MKQFR(dst, qq, qx0v, qx1v, qx2v, qxsv) { \
        const float* xp = Xp + (size_t)(bofs + (qq)) * 3; \
        qx0v = xp[0]; qx1v = xp[1]; qx2v = xp[2]; \
        qxsv = (qx0v * qx0v + qx1v * qx1v) + qx2v * qx2v; \
        uint16_t Xa, Xb; split2(qxsv, &Xa, &Xb); \
        uint16_t h0, m0; split2(qx0v, &h0, &m0); \
        uint16_t h1, m1; split2(qx1v, &h1, &m1); \
        uint16_t h2, m2; split2(qx2v, &h2, &m2); \
        const uint16_t ONE = 0x3F80; \
        if (hi == 0) { \
            dst[0]=(short)Xa; dst[1]=(short)Xb; dst[2]=(short)ONE; dst[3]=(short)ONE; \
            dst[4]=(short)h0; dst[5]=(short)h0; dst[6]=(short)m0;  dst[7]=(short)m0; \
        } else { \
            dst[0]=(short)h1; dst[1]=(short)h1; dst[2]=(short)m1;  dst[3]=(short)m1; \
            dst[4]=(short)h2; dst[5]=(short)h2; dst[6]=(short)m2;  dst[7]=(short)m2; \
        } }

// ============ sweep 1: per-query approx min -> mkey (u32 order keys) ============
__global__ __launch_bounds__(256, 4) void nn_sweep1(
    const float* __restrict__ xyz1, const float* __restrict__ xyz2,
    const uint4* __restrict__ encA, const uint4* __restrict__ encB,
    uint32_t* __restrict__ mkey, int ksplit)
{
#pragma clang fp contract(off)
    __shared__ uint4 lds[2][2 * CH];                   // 2 x 8 KB

    const int tid = threadIdx.x;
    const int l   = tid & 63;
    const int wv  = tid >> 6;
    const int col = l & 31;
    const int hi  = l >> 5;
    DECODE_DBX()

    const float* Xp = dir ? xyz2 : xyz1;
    const uint4* ep = (dir ? encB : encA) + (size_t)batch * (NCH * 2 * CH);
    const int bofs  = batch * NPTS;
    const int qbase = xblk * QPB + wv * 64;
    const int chalf = NCH / ksplit;
    const int c0 = kh * chalf, c1 = c0 + chalf;

    const f32x16 zf = {0.f,0.f,0.f,0.f,0.f,0.f,0.f,0.f,
                       0.f,0.f,0.f,0.f,0.f,0.f,0.f,0.f};

    s16x8 qfr0, qfr1;
    float qa0, qa1, qa2, qas, qb0, qb1, qb2, qbs;
    MKQFR(qfr0, qbase + col,      qa0, qa1, qa2, qas)
    MKQFR(qfr1, qbase + 32 + col, qb0, qb1, qb2, qbs)
    (void)qa0; (void)qb0;

    const int ldsb = hi * CH + col;

    float run0 = __builtin_inff(), run1 = __builtin_inff();
    STAGE(c0, 0);
    __syncthreads();
    int cur = 0;
    for (int c = c0; c < c1; ++c) {
        if (c + 1 < c1) STAGE(c + 1, cur ^ 1);
#pragma unroll
        for (int tp = 0; tp < CH / 64; ++tp) {
            const s16x8 pA = *(const s16x8*)&lds[cur][ldsb + (2 * tp) * 32];
            const s16x8 pB = *(const s16x8*)&lds[cur][ldsb + (2 * tp + 1) * 32];
            const f32x16 a0 = __builtin_amdgcn_mfma_f32_32x32x16_bf16(pA, qfr0, zf, 0, 0, 0);
            const f32x16 a1 = __builtin_amdgcn_mfma_f32_32x32x16_bf16(pA, qfr1, zf, 0, 0, 0);
            const f32x16 a2 = __builtin_amdgcn_mfma_f32_32x32x16_bf16(pB, qfr0, zf, 0, 0, 0);
            const f32x16 a3 = __builtin_amdgcn_mfma_f32_32x32x16_bf16(pB, qfr1, zf, 0, 0, 0);
            run0 = MIN3(run0, fold16(a0), fold16(a2));
            run1 = MIN3(run1, fold16(a1), fold16(a3));
        }
        __syncthreads();
        cur ^= 1;
    }
    run0 = fminf(run0, __shfl_xor(run0, 32, 64));
    run1 = fminf(run1, __shfl_xor(run1, 32, 64));
    if (l < 32) {
        uint32_t* mp = mkey + (size_t)dir * BN + bofs + qbase;
        atomicMin(&mp[col],      key32(run0));
        atomicMin(&mp[32 + col], key32(run1));
    }
}

// ====== sweep 2: candidates (approx d <= m'+MARGIN) + exact argmin ======
__global__ __launch_bounds__(256, 4) void nn_sweep2(
    const float* __restrict__ xyz1, const float* __restrict__ xyz2,
    const uint4* __restrict__ encA, const uint4* __restrict__ encB,
    const uint32_t* __restrict__ mkey, unsigned long long* __restrict__ gkeys,
    float* __restrict__ out, int ksplit)
{
#pragma clang fp contract(off)
    __shared__ uint4 lds[2][2 * CH];                   // 2 x 8 KB
    __shared__ unsigned long long keys[QPB];           // 2 KB

    const int tid = threadIdx.x;
    const int l   = tid & 63;
    const int wv  = tid >> 6;
    const int col = l & 31;
    const int hi  = l >> 5;
    DECODE_DBX()

    const float* Xp = dir ? xyz2 : xyz1;
    const float* Yp = dir ? xyz1 : xyz2;
    const uint4* ep = (dir ? encB : encA) + (size_t)batch * (NCH * 2 * CH);
    const int bofs  = batch * NPTS;
    const int qbase = xblk * QPB + wv * 64;
    const int chalf = NCH / ksplit;
    const int c0 = kh * chalf, c1 = c0 + chalf;

    keys[tid] = ~0ull;

    const f32x16 zf = {0.f,0.f,0.f,0.f,0.f,0.f,0.f,0.f,
                       0.f,0.f,0.f,0.f,0.f,0.f,0.f,0.f};

    // A-side (point) row calibration, packed 16 x 8 bits
    int rowpack[4] = {0, 0, 0, 0};
    {
        s16x8 pa = {0,0,0,0,0,0,0,0}, pb = {0,0,0,0,0,0,0,0};
        if (hi == 0) { pa[0] = (short)bfr((float)col); pb[0] = (short)0x3F80; }
        const f32x16 rowp = __builtin_amdgcn_mfma_f32_32x32x16_bf16(pa, pb, zf, 0, 0, 0);
#define PR(i) rowpack[(i) >> 2] |= ((int)rowp[i] & 0xFF) << (((i) & 3) * 8);
        F16(PR)
#undef PR
    }

    s16x8 qfr0, qfr1;
    float qa0, qa1, qa2, qas, qb0, qb1, qb2, qbs;
    MKQFR(qfr0, qbase + col,      qa0, qa1, qa2, qas)
    MKQFR(qfr1, qbase + 32 + col, qb0, qb1, qb2, qbs)

    float thr0, thr1;
    {
        const uint32_t* mp = mkey + (size_t)dir * BN + bofs + qbase;
        thr0 = dec32(mp[col]) + MARGIN;
        thr1 = dec32(mp[32 + col]) + MARGIN;
    }

    const int ldsb = hi * CH + col;

#define HITR(accv, jb, foff, thr, qx0, qx1, qx2, qxs, r) \
        if ((accv)[r] <= (thr)) { \
            const int jc = (jb) + ((rowpack[(r) >> 2] >> (((r) & 3) * 8)) & 0xFF); \
            const float* yq = Yp + (size_t)(bofs + jc) * 3; \
            const float py0 = yq[0], py1 = yq[1], py2 = yq[2]; \
            const float pys = (py0 * py0 + py1 * py1) + py2 * py2; \
            const float dd = ((qxs) - 2.0f * (((qx0) * py0 + (qx1) * py1) + (qx2) * py2)) + pys; \
            atomicMin(&keys[wv * 64 + (foff) + col], \
                      ((unsigned long long)key32(dd) << 32) | (uint32_t)jc); }
#define HIT(accv, jb, foff, thr, qx0, qx1, qx2, qxs) \
        if (fold16(accv) <= (thr)) { \
            HITR(accv, jb, foff, thr, qx0, qx1, qx2, qxs, 0) \
            HITR(accv, jb, foff, thr, qx0, qx1, qx2, qxs, 1) \
            HITR(accv, jb, foff, thr, qx0, qx1, qx2, qxs, 2) \
            HITR(accv, jb, foff, thr, qx0, qx1, qx2, qxs, 3) \
            HITR(accv, jb, foff, thr, qx0, qx1, qx2, qxs, 4) \
            HITR(accv, jb, foff, thr, qx0, qx1, qx2, qxs, 5) \
            HITR(accv, jb, foff, thr, qx0, qx1, qx2, qxs, 6) \
            HITR(accv, jb, foff, thr, qx0, qx1, qx2, qxs, 7) \
            HITR(accv, jb, foff, thr, qx0, qx1, qx2, qxs, 8) \
            HITR(accv, jb, foff, thr, qx0, qx1, qx2, qxs, 9) \
            HITR(accv, jb, foff, thr, qx0, qx1, qx2, qxs, 10) \
            HITR(accv, jb, foff, thr, qx0, qx1, qx2, qxs, 11) \
            HITR(accv, jb, foff, thr, qx0, qx1, qx2, qxs, 12) \
            HITR(accv, jb, foff, thr, qx0, qx1, qx2, qxs, 13) \
            HITR(accv, jb, foff, thr, qx0, qx1, qx2, qxs, 14) \
            HITR(accv, jb, foff, thr, qx0, qx1, qx2, qxs, 15) \
        }

    STAGE(c0, 0);
    __syncthreads();
    int cur = 0;
    for (int c = c0; c < c1; ++c) {
        if (c + 1 < c1) STAGE(c + 1, cur ^ 1);
#pragma unroll
        for (int tp = 0; tp < CH / 64; ++tp) {
            const s16x8 pA = *(const s16x8*)&lds[cur][ldsb + (2 * tp) * 32];
            const s16x8 pB = *(const s16x8*)&lds[cur][ldsb + (2 * tp + 1) * 32];
            const int jbA = c * CH + (2 * tp) * 32;
            {
                const f32x16 a0 = __builtin_amdgcn_mfma_f32_32x32x16_bf16(pA, qfr0, zf, 0, 0, 0);
                const f32x16 a2 = __builtin_amdgcn_mfma_f32_32x32x16_bf16(pB, qfr0, zf, 0, 0, 0);
                HIT(a0, jbA,      0, thr0, qa0, qa1, qa2, qas)
                HIT(a2, jbA + 32, 0, thr0, qa0, qa1, qa2, qas)
            }
            {
                const f32x16 a1 = __builtin_amdgcn_mfma_f32_32x32x16_bf16(pA, qfr1, zf, 0, 0, 0);
                const f32x16 a3 = __builtin_amdgcn_mfma_f32_32x32x16_bf16(pB, qfr1, zf, 0, 0, 0);
                HIT(a1, jbA,      32, thr1, qb0, qb1, qb2, qbs)
                HIT(a3, jbA + 32, 32, thr1, qb0, qb1, qb2, qbs)
            }
        }
        __syncthreads();
        cur ^= 1;
    }
#undef HIT
#undef HITR

    __syncthreads();
    {
        const unsigned long long m = keys[tid];
        const size_t gq = (size_t)dir * BN + bofs + (size_t)xblk * QPB + tid;
        if (ksplit == 2) {
            atomicMin(&gkeys[gq], m);          // merge the two k-halves
        } else {
            const uint32_t k32 = (uint32_t)(m >> 32);
            const size_t q = (size_t)bofs + (size_t)xblk * QPB + tid;
            out[(size_t)dir * BN + q]       = dec32(k32);
            out[(size_t)(2 + dir) * BN + q] = (float)(uint32_t)(m & 0xFFFFFFFFu);
        }
    }
}

// ---- final: gkeys -> (dist, idx) ----
__global__ __launch_bounds__(256) void writeout_k(
    const unsigned long long* __restrict__ gkeys, float* __restrict__ out)
{
    const size_t i = (size_t)blockIdx.x * 256 + threadIdx.x;   // 0..2*BN-1
    const unsigned long long m = gkeys[i];
    const int dir = (int)(i / BN);
    const size_t q = i - (size_t)dir * BN;
    out[(size_t)dir * BN + q]       = dec32((uint32_t)(m >> 32));
    out[(size_t)(2 + dir) * BN + q] = (float)(uint32_t)(m & 0xFFFFFFFFu);
}

extern "C" void kernel_launch(void* const* d_in, const int* in_sizes, int n_in,
                              void* d_out, int out_size, void* d_ws, size_t ws_size,
                              hipStream_t stream) {
    const float* xyz1 = (const float*)d_in[0];
    const float* xyz2 = (const float*)d_in[1];
    float* out = (float*)d_out;

    uint4*    encA  = (uint4*)d_ws;                        // 4 MiB
    uint4*    encB  = encA + (size_t)BN * 2;               // 4 MiB
    uint32_t* mkey  = (uint32_t*)(encB + (size_t)BN * 2);  // 1 MiB
    unsigned long long* gkeys = (unsigned long long*)(mkey + (size_t)2 * BN); // 2 MiB

    enc_kernel<<<BN / 256, 256, 0, stream>>>(xyz2, encA);
    enc_kernel<<<BN / 256, 256, 0, stream>>>(xyz1, encB);

    if (ws_size >= (size_t)11 * 1024 * 1024) {
        // k-split path: memset mkey (1MB) + gkeys (2MB) to all-ones = +inf keys
        hipMemsetAsync(mkey, 0xFF, (size_t)3 * 1024 * 1024, stream);
        nn_sweep1<<<2048, 256, 0, stream>>>(xyz1, xyz2, encA, encB, mkey, 2);
        nn_sweep2<<<2048, 256, 0, stream>>>(xyz1, xyz2, encA, encB, mkey, gkeys, out, 2);
        writeout_k<<<(2 * BN) / 256, 256, 0, stream>>>(gkeys, out);
    } else {
        hipMemsetAsync(mkey, 0xFF, (size_t)1024 * 1024, stream);
        nn_sweep1<<<1024, 256, 0, stream>>>(xyz1, xyz2, encA, encB, mkey, 1);
        nn_sweep2<<<1024, 256, 0, stream>>>(xyz1, xyz2, encA, encB, mkey, nullptr, out, 1);
    }
}